// Round 19
// baseline (46.870 us; speedup 1.0000x reference)
//
#include <hip/hip_runtime.h>

// Voxelizer: V = 64^3 voxels over [-1,1]^3, N = 4096 anisotropic Gaussians.
// out[v] = packed bf16 pair: low16 = sum(resp*dB), high16 = sum(resp*dA),
//   resp = exp2(q), q = degree-2 poly in voxel coords (-0.5*log2(e) folded in).
//
// Layout (established r0-r18, PASSING since r6):
//   d_in : fp32. [0] pos [N,3], [1] cov [N,3,3], [2] dA, [3] dB
//   d_out: 524288 bf16 = u32 per voxel (low=dB-sum, high=dA-sum)
//
// r18 post-mortem: 45.5us (accum 39); block lifetime 2.4us vs 1.4 modeled --
// 1-deep group prefetch under-covers L2 latency at btest boundaries.
// r19: 2-deep prefetch -- fully unrolled group loop with A/B register sets;
//      group g issues loads for g+2; coverage = one full group (~1k cyc).

#ifndef __has_builtin
#define __has_builtin(x) 0
#endif

typedef float v2f __attribute__((ext_vector_type(2)));

using u16 = unsigned short;
using u32 = unsigned int;
using u64 = unsigned long long;

constexpr int   VTOT = 64 * 64 * 64;
constexpr float QCUT = -10.0f;       // drop pairs with resp < 2^-10

__device__ __forceinline__ u16 f2bf(float f) {   // fp32 -> bf16, RNE
    u32 x = __float_as_uint(f);
    x += 0x7FFFu + ((x >> 16) & 1u);
    return (u16)(x >> 16);
}

__device__ __forceinline__ float exp2_fast(float x) {
#if __has_builtin(__builtin_amdgcn_exp2f)
    return __builtin_amdgcn_exp2f(x);            // v_exp_f32
#else
    return exp2f(x);
#endif
}

__device__ __forceinline__ v2f pkfma(v2f a, v2f b, v2f c) {
#if __has_builtin(__builtin_elementwise_fma)
    return __builtin_elementwise_fma(a, b, c);   // -> v_pk_fma_f32
#else
    v2f r; r.x = fmaf(a.x, b.x, c.x); r.y = fmaf(a.y, b.y, c.y); return r;
#endif
}

// conservative reachability; layout:
// F0=(kz,kzy,kx,kxy) F1=(k0,ky,kzz,kxx) F2=(kzx,kyy,dA,dB)
__device__ __forceinline__ bool btest(float4 F0, float4 F1, float4 F2,
                                      float zc, float xc, float yc,
                                      float hz, float hx, float hy)
{
    float kz = F0.x, kzy = F0.y, kx = F0.z, kxy = F0.w;
    float k0 = F1.x, ky = F1.y, kzz = F1.z, kxx = F1.w;
    float kzx = F2.x, kyy = F2.y;
    float bc = fmaf(kz, zc, k0);
    bc = fmaf(kzz, zc * zc, bc);
    bc = fmaf(kx, xc, bc);
    bc = fmaf(kxx, xc * xc, bc);
    bc = fmaf(kzx, zc * xc, bc);
    float cy0 = fmaf(kzy, zc, ky);
    cy0 = fmaf(kxy, xc, cy0);
    float qc = fmaf(kyy, yc * yc, fmaf(cy0, yc, bc));
    float gz = fmaf(2.0f * kzz, zc, kz);
    gz = fmaf(kzx, xc, gz); gz = fmaf(kzy, yc, gz);
    float gx = fmaf(2.0f * kxx, xc, kx);
    gx = fmaf(kzx, zc, gx); gx = fmaf(kxy, yc, gx);
    float gy = fmaf(2.0f * kyy, yc, ky);
    gy = fmaf(kzy, zc, gy); gy = fmaf(kxy, xc, gy);
    float margin = fmaf(fabsf(gz), hz, fmaf(fabsf(gx), hx, fabsf(gy) * hy));
    return (qc + margin > QCUT);
}

// ---------------- prepass: coefficients + recurrence constants -----------
// entry n: F0=(kz,kzy,kx,kxy) F1=(k0,ky,kzz,kxx) F2=(kzx,kyy,dA,dB)
//          F3=(u, kyyS2, k2s, u^4)  with u=exp2(2 kyy s^2), s=2/63
__global__ __launch_bounds__(256) void vox_prep(
    const float* __restrict__ pos, const float* __restrict__ cov,
    const float* __restrict__ dA,  const float* __restrict__ dB,
    float4* __restrict__ cft, int N)
{
    int n = blockIdx.x * 256 + threadIdx.x;
    if (n >= N) return;
    const float sc = -0.7213475204444817f;   // -0.5 * log2(e)
    const float step = 2.0f / 63.0f;
    const float S2 = step * step;
    float p0 = pos[3 * n + 0], p1 = pos[3 * n + 1], p2 = pos[3 * n + 2];
    const float* c = cov + 9 * n;
    float c00 = c[0], c01 = c[1], c02 = c[2];
    float c10 = c[3], c11 = c[4], c12 = c[5];
    float c20 = c[6], c21 = c[7], c22 = c[8];
    float s01 = c01 + c10, s02 = c02 + c20, s12 = c12 + c21;
    float k0 = sc * (c00 * p0 * p0 + c11 * p1 * p1 + c22 * p2 * p2
                     + s01 * p0 * p1 + s02 * p0 * p2 + s12 * p1 * p2);
    float kz = -sc * (2.0f * c00 * p0 + s01 * p1 + s02 * p2);
    float kx = -sc * (s01 * p0 + 2.0f * c11 * p1 + s12 * p2);
    float ky = -sc * (s02 * p0 + s12 * p1 + 2.0f * c22 * p2);
    float kyy = sc * c22;
    float u = exp2f(2.0f * kyy * S2);
    float u2 = u * u;
    cft[4 * n + 0] = make_float4(kz, sc * s02, kx, sc * s12);
    cft[4 * n + 1] = make_float4(k0, ky, sc * c00, sc * c11);
    cft[4 * n + 2] = make_float4(sc * s01, kyy, dA[n], dB[n]);
    cft[4 * n + 3] = make_float4(u, kyy * S2, kyy * (2.0f * step), u2 * u2);
}

// ---------------- accum<SPLIT>: wave-local lists, 2-deep prefetch --------
// 1024*SPLIT blocks x 256 threads (4 waves). Brick 4z x 8x x 8y.
// Wave qw owns gaussians [gbase + qw*GPW, +GPW) in 64-wide groups:
// btest -> wave-local compact into own segment -> inner loop (lanes 0-31
// take entry 2i, 32-63 take 2i+1). Group loop fully unrolled with A/B
// register sets; group g issues loads for g+2. No main-loop barriers.
template <int SPLIT>
__global__ __launch_bounds__(256, 4) void vox_accum(
    const float4* __restrict__ cft,  // [N*4] coefficient table
    float2* __restrict__ pws)        // [SPLIT*VTOT] (A,B) partials
{
    constexpr int GPS    = 4096 / SPLIT;     // gaussians per split
    constexpr int GPW    = GPS / 4;          // per wave
    constexpr int GROUPS = GPW / 64;
    constexpr int LOG    = (SPLIT == 4) ? 2 : 1;
    constexpr int SEGF4  = 65 * 5;           // 65 entries x 5 float4 = 5200B

    __shared__ alignas(16) unsigned char smem[20864];  // 4*5200 U cbuf(18432)
    float4* sglbase = reinterpret_cast<float4*>(smem);
    typedef float2 crow_t[32][9];
    crow_t* cbuf = reinterpret_cast<crow_t*>(smem);    // [8][32][9] f2

    const int t    = threadIdx.x;
    const int qw   = t >> 6;
    const int lane = t & 63;
    const int sub  = lane >> 5;
    const int slot = lane & 31;
    const int sub2 = qw * 2 + sub;
    const int w    = blockIdx.x;
    const int h    = w & (SPLIT - 1);
    const int bi   = w >> LOG;
    // center-out brick mapping (LPT dispatch order)
    const int i16 = bi >> 6, i8x = (bi >> 3) & 7, i8y = bi & 7;
    const int bz = (i16 & 1) ? 8 + (i16 >> 1) : 7 - (i16 >> 1);
    const int bx = (i8x & 1) ? 4 + (i8x >> 1) : 3 - (i8x >> 1);
    const int by = (i8y & 1) ? 4 + (i8y >> 1) : 3 - (i8y >> 1);

    const int dz = slot >> 3, dx = slot & 7;
    const int iz = bz * 4 + dz, ix = bx * 8 + dx, iy0 = by * 8;

    const float step = 2.0f / 63.0f;
    const float z = -1.0f + step * (float)iz;
    const float x = -1.0f + step * (float)ix;
    const float zz = z * z, xx = x * x, zx = z * x;
    const float y0v = -1.0f + step * (float)(iy0);
    const float y4v = -1.0f + step * (float)(iy0 + 4);
    const v2f Y04  = {y0v, y4v};
    const v2f YY04 = {y0v * y0v, y4v * y4v};
    const v2f z2 = {z, z}, x2 = {x, x};

    const float zc = -1.0f + step * ((float)(bz * 4) + 1.5f);
    const float xc = -1.0f + step * ((float)(bx * 8) + 3.5f);
    const float yc = -1.0f + step * ((float)(by * 8) + 3.5f);
    const float hz = 1.5f * step, hx = 3.5f * step, hy = 3.5f * step;

    const u64 lmask = (1ull << lane) - 1ull;
    const int gw = h * GPS + qw * GPW;       // this wave's gaussian base
    float4* seg = sglbase + qw * SEGF4;      // this wave's segment

    // preload groups 0 (A) and 1 (B)
    int nA = gw + lane;
    float4 gA0 = cft[4 * nA + 0], gA1 = cft[4 * nA + 1],
           gA2 = cft[4 * nA + 2], gA3 = cft[4 * nA + 3];
    int nB = gw + 64 + lane;
    float4 gB0 = cft[4 * nB + 0], gB1 = cft[4 * nB + 1],
           gB2 = cft[4 * nB + 2], gB3 = cft[4 * nB + 3];

    v2f acc[8];
#pragma unroll
    for (int i = 0; i < 8; ++i) acc[i] = v2f{0.f, 0.f};

#pragma unroll
    for (int g = 0; g < GROUPS; ++g) {
        const bool useA = ((g & 1) == 0);
        float4 ca = useA ? gA0 : gB0;
        float4 cb = useA ? gA1 : gB1;
        float4 cc = useA ? gA2 : gB2;
        float4 cd = useA ? gA3 : gB3;

        // ---- test + wave-local compact (no cross-wave sync) ----
        bool p = btest(ca, cb, cc, zc, xc, yc, hz, hx, hy);
        u64 m = __ballot(p);
        int rank = __popcll(m & lmask);
        int cnt  = __popcll(m);
        if (p) {
            seg[5 * rank + 0] = ca;
            seg[5 * rank + 1] = cb;
            seg[5 * rank + 2] = cc;
            seg[5 * rank + 3] = cd;
        }
        if (lane == 0 && (cnt & 1)) {        // zero-pad odd count
            const float4 zf4 = make_float4(0.f, 0.f, 0.f, 0.f);
            seg[5 * cnt + 0] = zf4;
            seg[5 * cnt + 1] = zf4;
            seg[5 * cnt + 2] = zf4;
            seg[5 * cnt + 3] = zf4;
        }

        // ---- issue loads for group g+2 into this parity's registers ----
        if (g + 2 < GROUPS) {
            int nn = gw + (g + 2) * 64 + lane;
            if (useA) {
                gA0 = cft[4 * nn + 0]; gA1 = cft[4 * nn + 1];
                gA2 = cft[4 * nn + 2]; gA3 = cft[4 * nn + 3];
            } else {
                gB0 = cft[4 * nn + 0]; gB1 = cft[4 * nn + 1];
                gB2 = cft[4 * nn + 2]; gB3 = cft[4 * nn + 3];
            }
        }

        const int iters = (cnt + 1) >> 1;
        // lanes 0-31 take entry 2i, lanes 32-63 take 2i+1 (2-way broadcast)
        for (int i = 0; i < iters; ++i) {
            const int j = 2 * i + sub;
            float4 w0 = seg[5 * j + 0];   // kz, kzy, kx, kxy
            float4 w1 = seg[5 * j + 1];   // k0, ky, kzz, kxx
            float4 w2 = seg[5 * j + 2];   // kzx, kyy, dA, dB
            float4 w3 = seg[5 * j + 3];   // u, kyyS2, k2s, u^4

            v2f mm = pkfma(v2f{w0.x, w0.y}, z2, v2f{w1.x, w1.y});
            mm = pkfma(v2f{w0.z, w0.w}, x2, mm);
            float bb = fmaf(w1.z, zz, mm.x);
            bb = fmaf(w1.w, xx, bb);
            bb = fmaf(w2.x, zx, bb);
            const float cy = mm.y;
            const float kyy = w2.y;

            v2f q04 = pkfma(v2f{kyy, kyy}, YY04,
                      pkfma(v2f{cy, cy}, Y04, v2f{bb, bb}));
            const float hc = fmaf(cy, step, w3.y);
            const float d0 = fmaf(w3.z, y0v, hc);

            const float t0 = exp2_fast(d0);
            v2f e  = {exp2_fast(q04.x), exp2_fast(q04.y)};
            v2f tt = {t0, t0 * w3.w};            // t4 = t0 * u^4
            const v2f uu  = {w3.x, w3.x};
            const v2f dab = {w2.z, w2.w};

            acc[0] = pkfma(v2f{e.x, e.x}, dab, acc[0]);
            acc[4] = pkfma(v2f{e.y, e.y}, dab, acc[4]);
            e = e * tt; tt = tt * uu;
            acc[1] = pkfma(v2f{e.x, e.x}, dab, acc[1]);
            acc[5] = pkfma(v2f{e.y, e.y}, dab, acc[5]);
            e = e * tt; tt = tt * uu;
            acc[2] = pkfma(v2f{e.x, e.x}, dab, acc[2]);
            acc[6] = pkfma(v2f{e.y, e.y}, dab, acc[6]);
            e = e * tt;
            acc[3] = pkfma(v2f{e.x, e.x}, dab, acc[3]);
            acc[7] = pkfma(v2f{e.y, e.y}, dab, acc[7]);
        }
    }

    __syncthreads();   // all waves done with seg before cbuf aliasing

    // ---- combine 8 substreams through LDS ----
#pragma unroll
    for (int i = 0; i < 8; ++i)
        cbuf[sub2][slot][i] = make_float2(acc[i].x, acc[i].y);
    __syncthreads();

    const int slot2 = t >> 3, yi = t & 7;    // one voxel per thread
    float A = 0.f, B = 0.f;
#pragma unroll
    for (int k = 0; k < 8; ++k) {
        float2 v = cbuf[k][slot2][yi];
        A += v.x; B += v.y;
    }
    const int iz2 = bz * 4 + (slot2 >> 3), ix2 = bx * 8 + (slot2 & 7);
    const int iy2 = by * 8 + yi;
    pws[h * VTOT + (iz2 * 64 + ix2) * 64 + iy2] = make_float2(A, B);
}

// ---------------- pack<SPLIT>: sum slabs, convert to bf16 ----------------
template <int SPLIT>
__global__ __launch_bounds__(256) void vox_pack(
    const float2* __restrict__ pws, u32* __restrict__ out)
{
    int v2 = blockIdx.x * 256 + threadIdx.x;     // 2 voxels per thread
    float A0 = 0.f, B0 = 0.f, A1 = 0.f, B1 = 0.f;
#pragma unroll
    for (int s = 0; s < SPLIT; ++s) {
        float4 a = ((const float4*)(pws + (size_t)s * VTOT))[v2];
        A0 += a.x; B0 += a.y; A1 += a.z; B1 += a.w;
    }
    uint2 o;
    o.x = (u32)f2bf(B0) | ((u32)f2bf(A0) << 16);
    o.y = (u32)f2bf(B1) | ((u32)f2bf(A1) << 16);
    *(uint2*)(out + 2 * v2) = o;
}

// ---------------- r11-style mid-tier ws fallback (stride-4 table) --------
constexpr int SEGCAP = 128;

__global__ __launch_bounds__(256, 4) void vox_main(
    const float4* __restrict__ cft, u32* __restrict__ out)
{
    __shared__ float4 sgl[4 * SEGCAP * 3];
    __shared__ int    wc[4];
    __shared__ float  cbuf[4][64][4][2];

    const int t = threadIdx.x, qw = t >> 6, lane = t & 63;
    const int b = (blockIdx.x * 331) & 1023;
    const int bz = b >> 6, bx = (b >> 3) & 7, by = b & 7;
    const int s = lane;
    const int dz = s >> 4, dx = (s >> 1) & 7, dyq = s & 1;
    const int iz = bz * 4 + dz, ix = bx * 8 + dx, iy0 = by * 8 + dyq * 4;

    const float step = 2.0f / 63.0f;
    const float z = -1.0f + step * (float)iz;
    const float x = -1.0f + step * (float)ix;
    const float zz = z * z, xx = x * x, zx = z * x;
    float y[4], yy[4];
#pragma unroll
    for (int i = 0; i < 4; ++i) {
        y[i] = -1.0f + step * (float)(iy0 + i);
        yy[i] = y[i] * y[i];
    }
    const float zc = -1.0f + step * ((float)(bz * 4) + 1.5f);
    const float xc = -1.0f + step * ((float)(bx * 8) + 3.5f);
    const float yc = -1.0f + step * ((float)(by * 8) + 3.5f);
    const float hz = 1.5f * step, hx = 3.5f * step, hy = 3.5f * step;
    const u64 lmask = (1ull << lane) - 1ull;

    int n0 = qw * 128 + lane;
    float4 g0a = cft[4 * n0 + 0], g0b = cft[4 * n0 + 1], g0c = cft[4 * n0 + 2];
    float4 g1a = cft[4 * (n0 + 64) + 0], g1b = cft[4 * (n0 + 64) + 1],
           g1c = cft[4 * (n0 + 64) + 2];

    float aA[4] = {0.f, 0.f, 0.f, 0.f};
    float aB[4] = {0.f, 0.f, 0.f, 0.f};

    for (int cb = 0; cb < 8; ++cb) {
        bool p0 = btest(g0a, g0b, g0c, zc, xc, yc, hz, hx, hy);
        bool p1 = btest(g1a, g1b, g1c, zc, xc, yc, hz, hx, hy);
        u64 m0 = __ballot(p0);
        u64 m1 = __ballot(p1);
        int r0 = __popcll(m0 & lmask);
        int c0 = __popcll(m0);
        int r1 = c0 + __popcll(m1 & lmask);
        int c1 = c0 + __popcll(m1);
        float4* segp = &sgl[qw * SEGCAP * 3];
        if (p0) { segp[3 * r0 + 0] = g0a; segp[3 * r0 + 1] = g0b; segp[3 * r0 + 2] = g0c; }
        if (p1) { segp[3 * r1 + 0] = g1a; segp[3 * r1 + 1] = g1b; segp[3 * r1 + 2] = g1c; }
        if (lane == 0) wc[qw] = c1;
        __syncthreads();

        if (cb < 7) {
            int nn = (cb + 1) * 512 + qw * 128 + lane;
            g0a = cft[4 * nn + 0]; g0b = cft[4 * nn + 1]; g0c = cft[4 * nn + 2];
            g1a = cft[4 * (nn + 64) + 0]; g1b = cft[4 * (nn + 64) + 1];
            g1c = cft[4 * (nn + 64) + 2];
        }
        int cnts[4] = {wc[0], wc[1], wc[2], wc[3]};
#pragma unroll
        for (int seg = 0; seg < 4; ++seg) {
            const float4* sp = &sgl[seg * SEGCAP * 3];
            const int cnt = cnts[seg];
#pragma unroll 2
            for (int j = qw; j < cnt; j += 4) {
                float4 w0 = sp[3 * j + 0];   // kz, kzy, kx, kxy
                float4 w1 = sp[3 * j + 1];   // k0, ky, kzz, kxx
                float4 w2 = sp[3 * j + 2];   // kzx, kyy, dA, dB
                float bb = fmaf(w0.x, z, w1.x);
                bb = fmaf(w1.z, zz, bb);
                bb = fmaf(w0.z, x, bb);
                bb = fmaf(w1.w, xx, bb);
                bb = fmaf(w2.x, zx, bb);
                float cy = fmaf(w0.y, z, w1.y);
                cy = fmaf(w0.w, x, cy);
#pragma unroll
                for (int i = 0; i < 4; ++i) {
                    float qv = fmaf(w2.y, yy[i], fmaf(cy, y[i], bb));
                    float rr = exp2_fast(qv);
                    aA[i] = fmaf(rr, w2.z, aA[i]);
                    aB[i] = fmaf(rr, w2.w, aB[i]);
                }
            }
        }
        __syncthreads();
    }
#pragma unroll
    for (int i = 0; i < 4; ++i) {
        cbuf[qw][s][i][0] = aA[i];
        cbuf[qw][s][i][1] = aB[i];
    }
    __syncthreads();
    const int s2 = t >> 2, i2 = t & 3;
    float A = cbuf[0][s2][i2][0] + cbuf[1][s2][i2][0]
            + cbuf[2][s2][i2][0] + cbuf[3][s2][i2][0];
    float B = cbuf[0][s2][i2][1] + cbuf[1][s2][i2][1]
            + cbuf[2][s2][i2][1] + cbuf[3][s2][i2][1];
    const int dz2 = s2 >> 4, dx2 = (s2 >> 1) & 7, dyq2 = s2 & 1;
    const int iz2 = bz * 4 + dz2, ix2 = bx * 8 + dx2;
    const int iy2 = by * 8 + dyq2 * 4 + i2;
    out[(iz2 * 64 + ix2) * 64 + iy2] = (u32)f2bf(B) | ((u32)f2bf(A) << 16);
}

// ---------------- last-resort fallback (no workspace, r9) ----------------
__global__ __launch_bounds__(256, 4) void vox_fallback(
    const float* __restrict__ pos, const float* __restrict__ cov,
    const float* __restrict__ dA,  const float* __restrict__ dB,
    u32* __restrict__ out, int N)
{
    __shared__ float4 sg[256 * 3];
    __shared__ float  cbuf[4][64][4][2];
    __shared__ int    wcnt[4];

    const int t = threadIdx.x, qw = t >> 6, lane = t & 63, s = lane;
    const int b = blockIdx.x;
    const int bz = b >> 6, bx = (b >> 3) & 7, by = b & 7;
    const int dz = s >> 4, dx = (s >> 1) & 7, dyq = s & 1;
    const int iz = bz * 4 + dz, ix = bx * 8 + dx, iy0 = by * 8 + dyq * 4;

    const float step = 2.0f / 63.0f;
    const float z = -1.0f + step * (float)iz;
    const float x = -1.0f + step * (float)ix;
    const float zz = z * z, xx = x * x, zx = z * x;
    float y[4], yy[4];
#pragma unroll
    for (int i = 0; i < 4; ++i) {
        y[i] = -1.0f + step * (float)(iy0 + i);
        yy[i] = y[i] * y[i];
    }
    const float zc = -1.0f + step * ((float)(bz * 4) + 1.5f);
    const float xc = -1.0f + step * ((float)(bx * 8) + 3.5f);
    const float yc = -1.0f + step * ((float)(by * 8) + 3.5f);
    const float hz = 1.5f * step, hx = 3.5f * step, hy = 3.5f * step;

    float aA[4] = {0.f, 0.f, 0.f, 0.f};
    float aB[4] = {0.f, 0.f, 0.f, 0.f};

    for (int cb = 0; cb < N; cb += 256) {
        int n = cb + t;
        bool pred = false;
        float4 F0, F1, F2;
        if (n < N) {
            const float sc = -0.7213475204444817f;
            float p0 = pos[3 * n + 0], p1 = pos[3 * n + 1], p2 = pos[3 * n + 2];
            const float* c = cov + 9 * n;
            float c00 = c[0], c01 = c[1], c02 = c[2];
            float c10 = c[3], c11 = c[4], c12 = c[5];
            float c20 = c[6], c21 = c[7], c22 = c[8];
            float s01 = c01 + c10, s02 = c02 + c20, s12 = c12 + c21;
            float k0 = sc * (c00 * p0 * p0 + c11 * p1 * p1 + c22 * p2 * p2
                             + s01 * p0 * p1 + s02 * p0 * p2 + s12 * p1 * p2);
            float kz = -sc * (2.0f * c00 * p0 + s01 * p1 + s02 * p2);
            float kx = -sc * (s01 * p0 + 2.0f * c11 * p1 + s12 * p2);
            float ky = -sc * (s02 * p0 + s12 * p1 + 2.0f * c22 * p2);
            F0 = make_float4(kz, sc * s02, kx, sc * s12);
            F1 = make_float4(k0, ky, sc * c00, sc * c11);
            F2 = make_float4(sc * s01, sc * c22, dA[n], dB[n]);
            pred = btest(F0, F1, F2, zc, xc, yc, hz, hx, hy);
        }
        u64 mask = __ballot(pred);
        int rank = __popcll(mask & ((1ull << lane) - 1ull));
        if (lane == 0) wcnt[qw] = __popcll(mask);
        __syncthreads();
        int off = 0;
#pragma unroll
        for (int w = 0; w < 4; ++w) if (w < qw) off += wcnt[w];
        const int total = wcnt[0] + wcnt[1] + wcnt[2] + wcnt[3];
        if (pred) {
            int p = off + rank;
            sg[3 * p + 0] = F0; sg[3 * p + 1] = F1; sg[3 * p + 2] = F2;
        }
        __syncthreads();
#pragma unroll 2
        for (int j = qw; j < total; j += 4) {
            float4 w0 = sg[3 * j + 0], w1 = sg[3 * j + 1], w2 = sg[3 * j + 2];
            float bb = fmaf(w0.x, z, w1.x);
            bb = fmaf(w1.z, zz, bb);
            bb = fmaf(w0.z, x, bb);
            bb = fmaf(w1.w, xx, bb);
            bb = fmaf(w2.x, zx, bb);
            float cy = fmaf(w0.y, z, w1.y);
            cy = fmaf(w0.w, x, cy);
#pragma unroll
            for (int i = 0; i < 4; ++i) {
                float qv = fmaf(w2.y, yy[i], fmaf(cy, y[i], bb));
                float rr = exp2_fast(qv);
                aA[i] = fmaf(rr, w2.z, aA[i]);
                aB[i] = fmaf(rr, w2.w, aB[i]);
            }
        }
        __syncthreads();
    }
#pragma unroll
    for (int i = 0; i < 4; ++i) {
        cbuf[qw][s][i][0] = aA[i];
        cbuf[qw][s][i][1] = aB[i];
    }
    __syncthreads();
    const int s2 = t >> 2, i2 = t & 3;
    float A = cbuf[0][s2][i2][0] + cbuf[1][s2][i2][0]
            + cbuf[2][s2][i2][0] + cbuf[3][s2][i2][0];
    float B = cbuf[0][s2][i2][1] + cbuf[1][s2][i2][1]
            + cbuf[2][s2][i2][1] + cbuf[3][s2][i2][1];
    const int dz2 = s2 >> 4, dx2 = (s2 >> 1) & 7, dyq2 = s2 & 1;
    const int iz2 = bz * 4 + dz2, ix2 = bx * 8 + dx2;
    const int iy2 = by * 8 + dyq2 * 4 + i2;
    out[(iz2 * 64 + ix2) * 64 + iy2] = (u32)f2bf(B) | ((u32)f2bf(A) << 16);
}

extern "C" void kernel_launch(void* const* d_in, const int* in_sizes, int n_in,
                              void* d_out, int out_size, void* d_ws, size_t ws_size,
                              hipStream_t stream)
{
    const float* pos = (const float*)d_in[0];
    const float* cov = (const float*)d_in[1];
    const float* dA  = (const float*)d_in[2];
    const float* dB  = (const float*)d_in[3];
    const int N = in_sizes[0] / 3;          // 4096

    const size_t CFT_BYTES  = (size_t)4096 * 64;          // 262144
    const size_t PWS2_BYTES = (size_t)2 * VTOT * 8;       // 4 MiB
    const size_t PWS4_BYTES = (size_t)4 * VTOT * 8;       // 8 MiB

    if (N == 4096 && ws_size >= CFT_BYTES + PWS4_BYTES) {
        float4* cft = (float4*)d_ws;
        float2* pws = (float2*)((char*)d_ws + CFT_BYTES);
        vox_prep<<<16, 256, 0, stream>>>(pos, cov, dA, dB, cft, N);
        vox_accum<4><<<4096, 256, 0, stream>>>(cft, pws);
        vox_pack<4><<<VTOT / 512, 256, 0, stream>>>(pws, (u32*)d_out);
    } else if (N == 4096 && ws_size >= CFT_BYTES + PWS2_BYTES) {
        float4* cft = (float4*)d_ws;
        float2* pws = (float2*)((char*)d_ws + CFT_BYTES);
        vox_prep<<<16, 256, 0, stream>>>(pos, cov, dA, dB, cft, N);
        vox_accum<2><<<2048, 256, 0, stream>>>(cft, pws);
        vox_pack<2><<<VTOT / 512, 256, 0, stream>>>(pws, (u32*)d_out);
    } else if (N == 4096 && ws_size >= CFT_BYTES) {
        float4* cft = (float4*)d_ws;
        vox_prep<<<16, 256, 0, stream>>>(pos, cov, dA, dB, cft, N);
        vox_main<<<1024, 256, 0, stream>>>(cft, (u32*)d_out);
    } else {
        vox_fallback<<<1024, 256, 0, stream>>>(pos, cov, dA, dB, (u32*)d_out, N);
    }
}

// Round 20
// 45.384 us; speedup vs baseline: 1.0327x; 1.0327x over previous
//
#include <hip/hip_runtime.h>

// Voxelizer: V = 64^3 voxels over [-1,1]^3, N = 4096 anisotropic Gaussians.
// out[v] = packed bf16 pair: low16 = sum(resp*dB), high16 = sum(resp*dA),
//   resp = exp2(q), q = degree-2 poly in voxel coords (-0.5*log2(e) folded in).
//
// Layout (established r0-r19, PASSING since r6):
//   d_in : fp32. [0] pos [N,3], [1] cov [N,3,3], [2] dA, [3] dB
//   d_out: 524288 bf16 = u32 per voxel (low=dB-sum, high=dA-sum)
//
// r19 post-mortem: 2-deep prefetch REGRESSED (+8 VGPR -> occupancy 33->28%,
// TLP loss > ILP gain). r20: exact revert to r18 (measured best, 45.5us):
// wave-local survivor lists, zero main-loop barriers, 1-deep prefetch,
// QCUT -10, dual-anchor exp2 y-recurrence (3 exps/iter), pk-math.

#ifndef __has_builtin
#define __has_builtin(x) 0
#endif

typedef float v2f __attribute__((ext_vector_type(2)));

using u16 = unsigned short;
using u32 = unsigned int;
using u64 = unsigned long long;

constexpr int   VTOT = 64 * 64 * 64;
constexpr float QCUT = -10.0f;       // drop pairs with resp < 2^-10

__device__ __forceinline__ u16 f2bf(float f) {   // fp32 -> bf16, RNE
    u32 x = __float_as_uint(f);
    x += 0x7FFFu + ((x >> 16) & 1u);
    return (u16)(x >> 16);
}

__device__ __forceinline__ float exp2_fast(float x) {
#if __has_builtin(__builtin_amdgcn_exp2f)
    return __builtin_amdgcn_exp2f(x);            // v_exp_f32
#else
    return exp2f(x);
#endif
}

__device__ __forceinline__ v2f pkfma(v2f a, v2f b, v2f c) {
#if __has_builtin(__builtin_elementwise_fma)
    return __builtin_elementwise_fma(a, b, c);   // -> v_pk_fma_f32
#else
    v2f r; r.x = fmaf(a.x, b.x, c.x); r.y = fmaf(a.y, b.y, c.y); return r;
#endif
}

// conservative reachability; layout:
// F0=(kz,kzy,kx,kxy) F1=(k0,ky,kzz,kxx) F2=(kzx,kyy,dA,dB)
__device__ __forceinline__ bool btest(float4 F0, float4 F1, float4 F2,
                                      float zc, float xc, float yc,
                                      float hz, float hx, float hy)
{
    float kz = F0.x, kzy = F0.y, kx = F0.z, kxy = F0.w;
    float k0 = F1.x, ky = F1.y, kzz = F1.z, kxx = F1.w;
    float kzx = F2.x, kyy = F2.y;
    float bc = fmaf(kz, zc, k0);
    bc = fmaf(kzz, zc * zc, bc);
    bc = fmaf(kx, xc, bc);
    bc = fmaf(kxx, xc * xc, bc);
    bc = fmaf(kzx, zc * xc, bc);
    float cy0 = fmaf(kzy, zc, ky);
    cy0 = fmaf(kxy, xc, cy0);
    float qc = fmaf(kyy, yc * yc, fmaf(cy0, yc, bc));
    float gz = fmaf(2.0f * kzz, zc, kz);
    gz = fmaf(kzx, xc, gz); gz = fmaf(kzy, yc, gz);
    float gx = fmaf(2.0f * kxx, xc, kx);
    gx = fmaf(kzx, zc, gx); gx = fmaf(kxy, yc, gx);
    float gy = fmaf(2.0f * kyy, yc, ky);
    gy = fmaf(kzy, zc, gy); gy = fmaf(kxy, xc, gy);
    float margin = fmaf(fabsf(gz), hz, fmaf(fabsf(gx), hx, fabsf(gy) * hy));
    return (qc + margin > QCUT);
}

// ---------------- prepass: coefficients + recurrence constants -----------
// entry n: F0=(kz,kzy,kx,kxy) F1=(k0,ky,kzz,kxx) F2=(kzx,kyy,dA,dB)
//          F3=(u, kyyS2, k2s, u^4)  with u=exp2(2 kyy s^2), s=2/63
__global__ __launch_bounds__(256) void vox_prep(
    const float* __restrict__ pos, const float* __restrict__ cov,
    const float* __restrict__ dA,  const float* __restrict__ dB,
    float4* __restrict__ cft, int N)
{
    int n = blockIdx.x * 256 + threadIdx.x;
    if (n >= N) return;
    const float sc = -0.7213475204444817f;   // -0.5 * log2(e)
    const float step = 2.0f / 63.0f;
    const float S2 = step * step;
    float p0 = pos[3 * n + 0], p1 = pos[3 * n + 1], p2 = pos[3 * n + 2];
    const float* c = cov + 9 * n;
    float c00 = c[0], c01 = c[1], c02 = c[2];
    float c10 = c[3], c11 = c[4], c12 = c[5];
    float c20 = c[6], c21 = c[7], c22 = c[8];
    float s01 = c01 + c10, s02 = c02 + c20, s12 = c12 + c21;
    float k0 = sc * (c00 * p0 * p0 + c11 * p1 * p1 + c22 * p2 * p2
                     + s01 * p0 * p1 + s02 * p0 * p2 + s12 * p1 * p2);
    float kz = -sc * (2.0f * c00 * p0 + s01 * p1 + s02 * p2);
    float kx = -sc * (s01 * p0 + 2.0f * c11 * p1 + s12 * p2);
    float ky = -sc * (s02 * p0 + s12 * p1 + 2.0f * c22 * p2);
    float kyy = sc * c22;
    float u = exp2f(2.0f * kyy * S2);
    float u2 = u * u;
    cft[4 * n + 0] = make_float4(kz, sc * s02, kx, sc * s12);
    cft[4 * n + 1] = make_float4(k0, ky, sc * c00, sc * c11);
    cft[4 * n + 2] = make_float4(sc * s01, kyy, dA[n], dB[n]);
    cft[4 * n + 3] = make_float4(u, kyy * S2, kyy * (2.0f * step), u2 * u2);
}

// ---------------- accum<SPLIT>: wave-local lists, barrier-free ----------
// 1024*SPLIT blocks x 256 threads (4 waves). Brick 4z x 8x x 8y.
// Wave qw owns gaussians [gbase + qw*GPW, +GPW), processed in 64-wide
// groups: btest (1/lane) -> wave-local compact into own segment ->
// inner loop over survivors (lanes 0-31 take entry 2i, 32-63 take 2i+1;
// odd cnt padded with one zero entry). No __syncthreads until combine.
template <int SPLIT>
__global__ __launch_bounds__(256, 4) void vox_accum(
    const float4* __restrict__ cft,  // [N*4] coefficient table
    float2* __restrict__ pws)        // [SPLIT*VTOT] (A,B) partials
{
    constexpr int GPS    = 4096 / SPLIT;     // gaussians per split
    constexpr int GPW    = GPS / 4;          // per wave
    constexpr int GROUPS = GPW / 64;
    constexpr int LOG    = (SPLIT == 4) ? 2 : 1;
    constexpr int SEGF4  = 65 * 5;           // 65 entries x 5 float4 = 5200B

    __shared__ alignas(16) unsigned char smem[20864];  // 4*5200 U cbuf(18432)
    float4* sglbase = reinterpret_cast<float4*>(smem);
    typedef float2 crow_t[32][9];
    crow_t* cbuf = reinterpret_cast<crow_t*>(smem);    // [8][32][9] f2

    const int t    = threadIdx.x;
    const int qw   = t >> 6;
    const int lane = t & 63;
    const int sub  = lane >> 5;
    const int slot = lane & 31;
    const int sub2 = qw * 2 + sub;
    const int w    = blockIdx.x;
    const int h    = w & (SPLIT - 1);
    const int bi   = w >> LOG;
    // center-out brick mapping (LPT dispatch order)
    const int i16 = bi >> 6, i8x = (bi >> 3) & 7, i8y = bi & 7;
    const int bz = (i16 & 1) ? 8 + (i16 >> 1) : 7 - (i16 >> 1);
    const int bx = (i8x & 1) ? 4 + (i8x >> 1) : 3 - (i8x >> 1);
    const int by = (i8y & 1) ? 4 + (i8y >> 1) : 3 - (i8y >> 1);

    const int dz = slot >> 3, dx = slot & 7;
    const int iz = bz * 4 + dz, ix = bx * 8 + dx, iy0 = by * 8;

    const float step = 2.0f / 63.0f;
    const float z = -1.0f + step * (float)iz;
    const float x = -1.0f + step * (float)ix;
    const float zz = z * z, xx = x * x, zx = z * x;
    const float y0v = -1.0f + step * (float)(iy0);
    const float y4v = -1.0f + step * (float)(iy0 + 4);
    const v2f Y04  = {y0v, y4v};
    const v2f YY04 = {y0v * y0v, y4v * y4v};
    const v2f z2 = {z, z}, x2 = {x, x};

    const float zc = -1.0f + step * ((float)(bz * 4) + 1.5f);
    const float xc = -1.0f + step * ((float)(bx * 8) + 3.5f);
    const float yc = -1.0f + step * ((float)(by * 8) + 3.5f);
    const float hz = 1.5f * step, hx = 3.5f * step, hy = 3.5f * step;

    const u64 lmask = (1ull << lane) - 1ull;
    const int gw = h * GPS + qw * GPW;       // this wave's gaussian base
    float4* seg = sglbase + qw * SEGF4;      // this wave's segment

    // prefetch group 0 (1 gaussian per lane)
    int n0 = gw + lane;
    float4 ga = cft[4 * n0 + 0], gb = cft[4 * n0 + 1],
           gc = cft[4 * n0 + 2], gd = cft[4 * n0 + 3];

    v2f acc[8];
#pragma unroll
    for (int i = 0; i < 8; ++i) acc[i] = v2f{0.f, 0.f};

    for (int g = 0; g < GROUPS; ++g) {
        // ---- test + wave-local compact (no cross-wave sync) ----
        bool p = btest(ga, gb, gc, zc, xc, yc, hz, hx, hy);
        u64 m = __ballot(p);
        int rank = __popcll(m & lmask);
        int cnt  = __popcll(m);
        if (p) {
            seg[5 * rank + 0] = ga;
            seg[5 * rank + 1] = gb;
            seg[5 * rank + 2] = gc;
            seg[5 * rank + 3] = gd;
        }
        if (lane == 0 && (cnt & 1)) {        // zero-pad odd count
            const float4 zf4 = make_float4(0.f, 0.f, 0.f, 0.f);
            seg[5 * cnt + 0] = zf4;
            seg[5 * cnt + 1] = zf4;
            seg[5 * cnt + 2] = zf4;
            seg[5 * cnt + 3] = zf4;
        }

        // ---- prefetch next group (overlaps with inner loop) ----
        if (g < GROUPS - 1) {
            int nn = gw + (g + 1) * 64 + lane;
            ga = cft[4 * nn + 0]; gb = cft[4 * nn + 1];
            gc = cft[4 * nn + 2]; gd = cft[4 * nn + 3];
        }

        const int iters = (cnt + 1) >> 1;
        // lanes 0-31 take entry 2i, lanes 32-63 take 2i+1 (2-way broadcast)
        for (int i = 0; i < iters; ++i) {
            const int j = 2 * i + sub;
            float4 w0 = seg[5 * j + 0];   // kz, kzy, kx, kxy
            float4 w1 = seg[5 * j + 1];   // k0, ky, kzz, kxx
            float4 w2 = seg[5 * j + 2];   // kzx, kyy, dA, dB
            float4 w3 = seg[5 * j + 3];   // u, kyyS2, k2s, u^4

            v2f mm = pkfma(v2f{w0.x, w0.y}, z2, v2f{w1.x, w1.y});
            mm = pkfma(v2f{w0.z, w0.w}, x2, mm);
            float bb = fmaf(w1.z, zz, mm.x);
            bb = fmaf(w1.w, xx, bb);
            bb = fmaf(w2.x, zx, bb);
            const float cy = mm.y;
            const float kyy = w2.y;

            v2f q04 = pkfma(v2f{kyy, kyy}, YY04,
                      pkfma(v2f{cy, cy}, Y04, v2f{bb, bb}));
            const float hc = fmaf(cy, step, w3.y);
            const float d0 = fmaf(w3.z, y0v, hc);

            const float t0 = exp2_fast(d0);
            v2f e  = {exp2_fast(q04.x), exp2_fast(q04.y)};
            v2f tt = {t0, t0 * w3.w};            // t4 = t0 * u^4
            const v2f uu  = {w3.x, w3.x};
            const v2f dab = {w2.z, w2.w};

            acc[0] = pkfma(v2f{e.x, e.x}, dab, acc[0]);
            acc[4] = pkfma(v2f{e.y, e.y}, dab, acc[4]);
            e = e * tt; tt = tt * uu;
            acc[1] = pkfma(v2f{e.x, e.x}, dab, acc[1]);
            acc[5] = pkfma(v2f{e.y, e.y}, dab, acc[5]);
            e = e * tt; tt = tt * uu;
            acc[2] = pkfma(v2f{e.x, e.x}, dab, acc[2]);
            acc[6] = pkfma(v2f{e.y, e.y}, dab, acc[6]);
            e = e * tt;
            acc[3] = pkfma(v2f{e.x, e.x}, dab, acc[3]);
            acc[7] = pkfma(v2f{e.y, e.y}, dab, acc[7]);
        }
    }

    __syncthreads();   // all waves done with seg before cbuf aliasing

    // ---- combine 8 substreams through LDS ----
#pragma unroll
    for (int i = 0; i < 8; ++i)
        cbuf[sub2][slot][i] = make_float2(acc[i].x, acc[i].y);
    __syncthreads();

    const int slot2 = t >> 3, yi = t & 7;    // one voxel per thread
    float A = 0.f, B = 0.f;
#pragma unroll
    for (int k = 0; k < 8; ++k) {
        float2 v = cbuf[k][slot2][yi];
        A += v.x; B += v.y;
    }
    const int iz2 = bz * 4 + (slot2 >> 3), ix2 = bx * 8 + (slot2 & 7);
    const int iy2 = by * 8 + yi;
    pws[h * VTOT + (iz2 * 64 + ix2) * 64 + iy2] = make_float2(A, B);
}

// ---------------- pack<SPLIT>: sum slabs, convert to bf16 ----------------
template <int SPLIT>
__global__ __launch_bounds__(256) void vox_pack(
    const float2* __restrict__ pws, u32* __restrict__ out)
{
    int v2 = blockIdx.x * 256 + threadIdx.x;     // 2 voxels per thread
    float A0 = 0.f, B0 = 0.f, A1 = 0.f, B1 = 0.f;
#pragma unroll
    for (int s = 0; s < SPLIT; ++s) {
        float4 a = ((const float4*)(pws + (size_t)s * VTOT))[v2];
        A0 += a.x; B0 += a.y; A1 += a.z; B1 += a.w;
    }
    uint2 o;
    o.x = (u32)f2bf(B0) | ((u32)f2bf(A0) << 16);
    o.y = (u32)f2bf(B1) | ((u32)f2bf(A1) << 16);
    *(uint2*)(out + 2 * v2) = o;
}

// ---------------- r11-style mid-tier ws fallback (stride-4 table) --------
constexpr int SEGCAP = 128;

__global__ __launch_bounds__(256, 4) void vox_main(
    const float4* __restrict__ cft, u32* __restrict__ out)
{
    __shared__ float4 sgl[4 * SEGCAP * 3];
    __shared__ int    wc[4];
    __shared__ float  cbuf[4][64][4][2];

    const int t = threadIdx.x, qw = t >> 6, lane = t & 63;
    const int b = (blockIdx.x * 331) & 1023;
    const int bz = b >> 6, bx = (b >> 3) & 7, by = b & 7;
    const int s = lane;
    const int dz = s >> 4, dx = (s >> 1) & 7, dyq = s & 1;
    const int iz = bz * 4 + dz, ix = bx * 8 + dx, iy0 = by * 8 + dyq * 4;

    const float step = 2.0f / 63.0f;
    const float z = -1.0f + step * (float)iz;
    const float x = -1.0f + step * (float)ix;
    const float zz = z * z, xx = x * x, zx = z * x;
    float y[4], yy[4];
#pragma unroll
    for (int i = 0; i < 4; ++i) {
        y[i] = -1.0f + step * (float)(iy0 + i);
        yy[i] = y[i] * y[i];
    }
    const float zc = -1.0f + step * ((float)(bz * 4) + 1.5f);
    const float xc = -1.0f + step * ((float)(bx * 8) + 3.5f);
    const float yc = -1.0f + step * ((float)(by * 8) + 3.5f);
    const float hz = 1.5f * step, hx = 3.5f * step, hy = 3.5f * step;
    const u64 lmask = (1ull << lane) - 1ull;

    int n0 = qw * 128 + lane;
    float4 g0a = cft[4 * n0 + 0], g0b = cft[4 * n0 + 1], g0c = cft[4 * n0 + 2];
    float4 g1a = cft[4 * (n0 + 64) + 0], g1b = cft[4 * (n0 + 64) + 1],
           g1c = cft[4 * (n0 + 64) + 2];

    float aA[4] = {0.f, 0.f, 0.f, 0.f};
    float aB[4] = {0.f, 0.f, 0.f, 0.f};

    for (int cb = 0; cb < 8; ++cb) {
        bool p0 = btest(g0a, g0b, g0c, zc, xc, yc, hz, hx, hy);
        bool p1 = btest(g1a, g1b, g1c, zc, xc, yc, hz, hx, hy);
        u64 m0 = __ballot(p0);
        u64 m1 = __ballot(p1);
        int r0 = __popcll(m0 & lmask);
        int c0 = __popcll(m0);
        int r1 = c0 + __popcll(m1 & lmask);
        int c1 = c0 + __popcll(m1);
        float4* segp = &sgl[qw * SEGCAP * 3];
        if (p0) { segp[3 * r0 + 0] = g0a; segp[3 * r0 + 1] = g0b; segp[3 * r0 + 2] = g0c; }
        if (p1) { segp[3 * r1 + 0] = g1a; segp[3 * r1 + 1] = g1b; segp[3 * r1 + 2] = g1c; }
        if (lane == 0) wc[qw] = c1;
        __syncthreads();

        if (cb < 7) {
            int nn = (cb + 1) * 512 + qw * 128 + lane;
            g0a = cft[4 * nn + 0]; g0b = cft[4 * nn + 1]; g0c = cft[4 * nn + 2];
            g1a = cft[4 * (nn + 64) + 0]; g1b = cft[4 * (nn + 64) + 1];
            g1c = cft[4 * (nn + 64) + 2];
        }
        int cnts[4] = {wc[0], wc[1], wc[2], wc[3]};
#pragma unroll
        for (int seg = 0; seg < 4; ++seg) {
            const float4* sp = &sgl[seg * SEGCAP * 3];
            const int cnt = cnts[seg];
#pragma unroll 2
            for (int j = qw; j < cnt; j += 4) {
                float4 w0 = sp[3 * j + 0];   // kz, kzy, kx, kxy
                float4 w1 = sp[3 * j + 1];   // k0, ky, kzz, kxx
                float4 w2 = sp[3 * j + 2];   // kzx, kyy, dA, dB
                float bb = fmaf(w0.x, z, w1.x);
                bb = fmaf(w1.z, zz, bb);
                bb = fmaf(w0.z, x, bb);
                bb = fmaf(w1.w, xx, bb);
                bb = fmaf(w2.x, zx, bb);
                float cy = fmaf(w0.y, z, w1.y);
                cy = fmaf(w0.w, x, cy);
#pragma unroll
                for (int i = 0; i < 4; ++i) {
                    float qv = fmaf(w2.y, yy[i], fmaf(cy, y[i], bb));
                    float rr = exp2_fast(qv);
                    aA[i] = fmaf(rr, w2.z, aA[i]);
                    aB[i] = fmaf(rr, w2.w, aB[i]);
                }
            }
        }
        __syncthreads();
    }
#pragma unroll
    for (int i = 0; i < 4; ++i) {
        cbuf[qw][s][i][0] = aA[i];
        cbuf[qw][s][i][1] = aB[i];
    }
    __syncthreads();
    const int s2 = t >> 2, i2 = t & 3;
    float A = cbuf[0][s2][i2][0] + cbuf[1][s2][i2][0]
            + cbuf[2][s2][i2][0] + cbuf[3][s2][i2][0];
    float B = cbuf[0][s2][i2][1] + cbuf[1][s2][i2][1]
            + cbuf[2][s2][i2][1] + cbuf[3][s2][i2][1];
    const int dz2 = s2 >> 4, dx2 = (s2 >> 1) & 7, dyq2 = s2 & 1;
    const int iz2 = bz * 4 + dz2, ix2 = bx * 8 + dx2;
    const int iy2 = by * 8 + dyq2 * 4 + i2;
    out[(iz2 * 64 + ix2) * 64 + iy2] = (u32)f2bf(B) | ((u32)f2bf(A) << 16);
}

// ---------------- last-resort fallback (no workspace, r9) ----------------
__global__ __launch_bounds__(256, 4) void vox_fallback(
    const float* __restrict__ pos, const float* __restrict__ cov,
    const float* __restrict__ dA,  const float* __restrict__ dB,
    u32* __restrict__ out, int N)
{
    __shared__ float4 sg[256 * 3];
    __shared__ float  cbuf[4][64][4][2];
    __shared__ int    wcnt[4];

    const int t = threadIdx.x, qw = t >> 6, lane = t & 63, s = lane;
    const int b = blockIdx.x;
    const int bz = b >> 6, bx = (b >> 3) & 7, by = b & 7;
    const int dz = s >> 4, dx = (s >> 1) & 7, dyq = s & 1;
    const int iz = bz * 4 + dz, ix = bx * 8 + dx, iy0 = by * 8 + dyq * 4;

    const float step = 2.0f / 63.0f;
    const float z = -1.0f + step * (float)iz;
    const float x = -1.0f + step * (float)ix;
    const float zz = z * z, xx = x * x, zx = z * x;
    float y[4], yy[4];
#pragma unroll
    for (int i = 0; i < 4; ++i) {
        y[i] = -1.0f + step * (float)(iy0 + i);
        yy[i] = y[i] * y[i];
    }
    const float zc = -1.0f + step * ((float)(bz * 4) + 1.5f);
    const float xc = -1.0f + step * ((float)(bx * 8) + 3.5f);
    const float yc = -1.0f + step * ((float)(by * 8) + 3.5f);
    const float hz = 1.5f * step, hx = 3.5f * step, hy = 3.5f * step;

    float aA[4] = {0.f, 0.f, 0.f, 0.f};
    float aB[4] = {0.f, 0.f, 0.f, 0.f};

    for (int cb = 0; cb < N; cb += 256) {
        int n = cb + t;
        bool pred = false;
        float4 F0, F1, F2;
        if (n < N) {
            const float sc = -0.7213475204444817f;
            float p0 = pos[3 * n + 0], p1 = pos[3 * n + 1], p2 = pos[3 * n + 2];
            const float* c = cov + 9 * n;
            float c00 = c[0], c01 = c[1], c02 = c[2];
            float c10 = c[3], c11 = c[4], c12 = c[5];
            float c20 = c[6], c21 = c[7], c22 = c[8];
            float s01 = c01 + c10, s02 = c02 + c20, s12 = c12 + c21;
            float k0 = sc * (c00 * p0 * p0 + c11 * p1 * p1 + c22 * p2 * p2
                             + s01 * p0 * p1 + s02 * p0 * p2 + s12 * p1 * p2);
            float kz = -sc * (2.0f * c00 * p0 + s01 * p1 + s02 * p2);
            float kx = -sc * (s01 * p0 + 2.0f * c11 * p1 + s12 * p2);
            float ky = -sc * (s02 * p0 + s12 * p1 + 2.0f * c22 * p2);
            F0 = make_float4(kz, sc * s02, kx, sc * s12);
            F1 = make_float4(k0, ky, sc * c00, sc * c11);
            F2 = make_float4(sc * s01, sc * c22, dA[n], dB[n]);
            pred = btest(F0, F1, F2, zc, xc, yc, hz, hx, hy);
        }
        u64 mask = __ballot(pred);
        int rank = __popcll(mask & ((1ull << lane) - 1ull));
        if (lane == 0) wcnt[qw] = __popcll(mask);
        __syncthreads();
        int off = 0;
#pragma unroll
        for (int w = 0; w < 4; ++w) if (w < qw) off += wcnt[w];
        const int total = wcnt[0] + wcnt[1] + wcnt[2] + wcnt[3];
        if (pred) {
            int p = off + rank;
            sg[3 * p + 0] = F0; sg[3 * p + 1] = F1; sg[3 * p + 2] = F2;
        }
        __syncthreads();
#pragma unroll 2
        for (int j = qw; j < total; j += 4) {
            float4 w0 = sg[3 * j + 0], w1 = sg[3 * j + 1], w2 = sg[3 * j + 2];
            float bb = fmaf(w0.x, z, w1.x);
            bb = fmaf(w1.z, zz, bb);
            bb = fmaf(w0.z, x, bb);
            bb = fmaf(w1.w, xx, bb);
            bb = fmaf(w2.x, zx, bb);
            float cy = fmaf(w0.y, z, w1.y);
            cy = fmaf(w0.w, x, cy);
#pragma unroll
            for (int i = 0; i < 4; ++i) {
                float qv = fmaf(w2.y, yy[i], fmaf(cy, y[i], bb));
                float rr = exp2_fast(qv);
                aA[i] = fmaf(rr, w2.z, aA[i]);
                aB[i] = fmaf(rr, w2.w, aB[i]);
            }
        }
        __syncthreads();
    }
#pragma unroll
    for (int i = 0; i < 4; ++i) {
        cbuf[qw][s][i][0] = aA[i];
        cbuf[qw][s][i][1] = aB[i];
    }
    __syncthreads();
    const int s2 = t >> 2, i2 = t & 3;
    float A = cbuf[0][s2][i2][0] + cbuf[1][s2][i2][0]
            + cbuf[2][s2][i2][0] + cbuf[3][s2][i2][0];
    float B = cbuf[0][s2][i2][1] + cbuf[1][s2][i2][1]
            + cbuf[2][s2][i2][1] + cbuf[3][s2][i2][1];
    const int dz2 = s2 >> 4, dx2 = (s2 >> 1) & 7, dyq2 = s2 & 1;
    const int iz2 = bz * 4 + dz2, ix2 = bx * 8 + dx2;
    const int iy2 = by * 8 + dyq2 * 4 + i2;
    out[(iz2 * 64 + ix2) * 64 + iy2] = (u32)f2bf(B) | ((u32)f2bf(A) << 16);
}

extern "C" void kernel_launch(void* const* d_in, const int* in_sizes, int n_in,
                              void* d_out, int out_size, void* d_ws, size_t ws_size,
                              hipStream_t stream)
{
    const float* pos = (const float*)d_in[0];
    const float* cov = (const float*)d_in[1];
    const float* dA  = (const float*)d_in[2];
    const float* dB  = (const float*)d_in[3];
    const int N = in_sizes[0] / 3;          // 4096

    const size_t CFT_BYTES  = (size_t)4096 * 64;          // 262144
    const size_t PWS2_BYTES = (size_t)2 * VTOT * 8;       // 4 MiB
    const size_t PWS4_BYTES = (size_t)4 * VTOT * 8;       // 8 MiB

    if (N == 4096 && ws_size >= CFT_BYTES + PWS4_BYTES) {
        float4* cft = (float4*)d_ws;
        float2* pws = (float2*)((char*)d_ws + CFT_BYTES);
        vox_prep<<<16, 256, 0, stream>>>(pos, cov, dA, dB, cft, N);
        vox_accum<4><<<4096, 256, 0, stream>>>(cft, pws);
        vox_pack<4><<<VTOT / 512, 256, 0, stream>>>(pws, (u32*)d_out);
    } else if (N == 4096 && ws_size >= CFT_BYTES + PWS2_BYTES) {
        float4* cft = (float4*)d_ws;
        float2* pws = (float2*)((char*)d_ws + CFT_BYTES);
        vox_prep<<<16, 256, 0, stream>>>(pos, cov, dA, dB, cft, N);
        vox_accum<2><<<2048, 256, 0, stream>>>(cft, pws);
        vox_pack<2><<<VTOT / 512, 256, 0, stream>>>(pws, (u32*)d_out);
    } else if (N == 4096 && ws_size >= CFT_BYTES) {
        float4* cft = (float4*)d_ws;
        vox_prep<<<16, 256, 0, stream>>>(pos, cov, dA, dB, cft, N);
        vox_main<<<1024, 256, 0, stream>>>(cft, (u32*)d_out);
    } else {
        vox_fallback<<<1024, 256, 0, stream>>>(pos, cov, dA, dB, (u32*)d_out, N);
    }
}